// Round 2
// baseline (533.223 us; speedup 1.0000x reference)
//
#include <hip/hip_runtime.h>

typedef __attribute__((ext_vector_type(8))) short s16x8;
typedef __attribute__((ext_vector_type(4))) float f32x4;
typedef unsigned short u16;

#define DEV __device__ __forceinline__

DEV u16 f2b(float f) {
  unsigned u = __builtin_bit_cast(unsigned, f);
  unsigned r = (u + 0x7FFFu + ((u >> 16) & 1u)) >> 16;
  return (u16)r;
}
DEV float b2f(u16 h) { return __builtin_bit_cast(float, (unsigned)h << 16); }
DEV f32x4 mfma16(s16x8 a, s16x8 b, f32x4 c) {
  return __builtin_amdgcn_mfma_f32_16x16x32_bf16(a, b, c, 0, 0, 0);
}
DEV float sigmoidf_(float x) { return 1.0f / (1.0f + expf(-x)); }

// async global -> LDS, 16B per lane (lds dest = wave-uniform base + lane*16)
DEV void g2l16(const u16* g, u16* l) {
  __builtin_amdgcn_global_load_lds((const __attribute__((address_space(1))) void*)g,
                                   (__attribute__((address_space(3))) void*)l, 16, 0, 0);
}

// ---------------------------------------------------------------- cast f32->bf16
__global__ __launch_bounds__(256) void cast_k(const float* __restrict__ s, u16* __restrict__ d) {
  size_t i = ((size_t)blockIdx.x * 256 + threadIdx.x) * 4;
  float4 v = *(const float4*)(s + i);
  ushort4 p; p.x = f2b(v.x); p.y = f2b(v.y); p.z = f2b(v.z); p.w = f2b(v.w);
  *(ushort4*)(d + i) = p;
}

// ---------------------------------------------------------------- rmsnorm (row = 1024)
__global__ __launch_bounds__(256) void rmsnorm_k(const float* __restrict__ x, u16* __restrict__ y) {
  const size_t row = blockIdx.x;
  const int tid = threadIdx.x;
  float4 v = ((const float4*)(x + row * 1024))[tid];
  float ss = v.x * v.x + v.y * v.y + v.z * v.z + v.w * v.w;
#pragma unroll
  for (int o = 32; o >= 1; o >>= 1) ss += __shfl_xor(ss, o);
  __shared__ float red[4];
  if ((tid & 63) == 0) red[tid >> 6] = ss;
  __syncthreads();
  float tot = red[0] + red[1] + red[2] + red[3];
  float rn = rsqrtf(tot * (1.0f / 1024.0f) + 1.1920929e-7f);
  ushort4 p;
  p.x = f2b(v.x * rn); p.y = f2b(v.y * rn); p.z = f2b(v.z * rn); p.w = f2b(v.w * rn);
  *(ushort4*)(y + row * 1024 + tid * 4) = p;
}

// ---------------------------------------------------------------- delta (3-phase chunked scan)
__global__ __launch_bounds__(256)
void delta_partial(const u16* __restrict__ y, const float* __restrict__ logits, float* __restrict__ Pp) {
  const int v = blockIdx.x * 256 + threadIdx.x;
  const int c = blockIdx.y, b = blockIdx.z;
  const float dec = sigmoidf_(logits[v]);
  const float ldc = logf(fmaxf(dec, 1e-6f));
  const u16* yp = y + ((size_t)b * 4096 + c * 128) * 1024 + v;
  float acc = 0.0f;
  for (int t = 0; t < 128; ++t) {
    float wgt = expf((float)(4095 - (c * 128 + t)) * ldc);
    acc += b2f(yp[(size_t)t * 1024]) * wgt;
  }
  Pp[((size_t)b * 32 + c) * 1024 + v] = acc;
}

__global__ __launch_bounds__(256) void delta_scan(float* __restrict__ Pp) {
  const int v = blockIdx.x * 256 + threadIdx.x;
  const int b = blockIdx.y;
  float run = 0.0f;
  for (int c = 0; c < 32; ++c) {
    size_t i = ((size_t)b * 32 + c) * 1024 + v;
    float t = Pp[i];
    Pp[i] = run;
    run += t;
  }
}

__global__ __launch_bounds__(256)
void delta_apply(const float* __restrict__ x0, const u16* __restrict__ y,
                 const float* __restrict__ logits, const float* __restrict__ scale_p,
                 const float* __restrict__ Pp, float* __restrict__ x1) {
  const int v = blockIdx.x * 256 + threadIdx.x;
  const int c = blockIdx.y, b = blockIdx.z;
  const float dec = sigmoidf_(logits[v]);
  const float ldc = logf(fmaxf(dec, 1e-6f));
  const float sc = scale_p[0];
  float carry = Pp[((size_t)b * 32 + c) * 1024 + v];
  size_t base = ((size_t)b * 4096 + c * 128) * 1024 + v;
  for (int t = 0; t < 128; ++t) {
    float wgt = expf((float)(4095 - (c * 128 + t)) * ldc);
    size_t idx = base + (size_t)t * 1024;
    x1[idx] = x0[idx] + carry / fmaxf(wgt, 1e-8f) * sc;
    carry += b2f(y[idx]) * wgt;
  }
}

// ---------------------------------------------------------------- GEMM: C[M,N] = A[M,K] * Bw[N,K]^T
// m97 structure: global_load_lds width-16 staging, linear [128][64] LDS tiles.
// EPI 0: store bf16 C
// EPI 1: store bf16 transposed into vT[B][256][4096]
// EPI 2: Xout = Xin + C*scale (fp32); optional Xb16 = bf16(Xout)
// EPI 3: Cb = bf16(gelu(C + bias[n]))
// EPI 4: Xout = Xin * sigmoid(C + bias[n])
template <int EPI>
__global__ __launch_bounds__(256)
void gemm_bt(const u16* __restrict__ A, const u16* __restrict__ Bw,
             int M, int N, int K,
             u16* __restrict__ Cb,
             const float* __restrict__ Xin, float* __restrict__ Xout,
             u16* __restrict__ Xb16,
             const float* __restrict__ bias, const float* __restrict__ scale_p) {
  __shared__ u16 sm[2 * 128 * 72];  // 36 KB; tiles use first 32 KB, EPI1 CT needs 34 KB
  u16* As = sm;                     // [128][64] linear
  u16* Bs = sm + 128 * 64;
  const int tid = threadIdx.x;
  const int n0 = blockIdx.x * 128, m0 = blockIdx.y * 128;
  const int wid = tid >> 6, lane = tid & 63;
  const int wm = (wid >> 1) * 64, wn = (wid & 1) * 64;
  const int lr = lane & 15, lk = (lane >> 4) * 8;
  const int srow = lane >> 3, scol = (lane & 7) * 8;  // staging: lane -> (row-in-8, col8)
  f32x4 acc[4][4] = {};
  for (int kt = 0; kt < K; kt += 64) {
#pragma unroll
    for (int p = 0; p < 4; ++p) {
      int c = wid * 4 + p;  // chunk 0..15, each = 8 rows x 64 cols
      g2l16(&A[(size_t)(m0 + c * 8 + srow) * K + kt + scol], &As[c * 512]);
      g2l16(&Bw[(size_t)(n0 + c * 8 + srow) * K + kt + scol], &Bs[c * 512]);
    }
    __syncthreads();
#pragma unroll
    for (int kk = 0; kk < 64; kk += 32) {
      s16x8 af[4], bfr[4];
#pragma unroll
      for (int i = 0; i < 4; ++i) af[i] = *(const s16x8*)&As[(wm + i * 16 + lr) * 64 + kk + lk];
#pragma unroll
      for (int j = 0; j < 4; ++j) bfr[j] = *(const s16x8*)&Bs[(wn + j * 16 + lr) * 64 + kk + lk];
#pragma unroll
      for (int i = 0; i < 4; ++i)
#pragma unroll
        for (int j = 0; j < 4; ++j) acc[i][j] = mfma16(af[i], bfr[j], acc[i][j]);
    }
    __syncthreads();
  }
  if constexpr (EPI == 1) {
    u16* CT = sm;  // reuse LDS: 128x136 bf16
#pragma unroll
    for (int i = 0; i < 4; ++i)
#pragma unroll
      for (int j = 0; j < 4; ++j)
#pragma unroll
        for (int r = 0; r < 4; ++r) {
          int ml = wm + i * 16 + (lane >> 4) * 4 + r;
          int nl = wn + j * 16 + lr;
          CT[nl * 136 + ml] = f2b(acc[i][j][r]);
        }
    __syncthreads();
    int nl = tid >> 1, off = (tid & 1) * 64;
    size_t base = ((size_t)(m0 >> 12) * 256 + n0 + nl) * 4096 + (m0 & 4095) + off;
#pragma unroll
    for (int p = 0; p < 8; ++p) *(uint4*)&Cb[base + p * 8] = *(const uint4*)&CT[nl * 136 + off + p * 8];
  } else {
    float sc = (EPI == 2) ? scale_p[0] : 0.0f;
#pragma unroll
    for (int i = 0; i < 4; ++i)
#pragma unroll
      for (int j = 0; j < 4; ++j)
#pragma unroll
        for (int r = 0; r < 4; ++r) {
          int m = m0 + wm + i * 16 + (lane >> 4) * 4 + r;
          int n = n0 + wn + j * 16 + lr;
          float c = acc[i][j][r];
          size_t idx = (size_t)m * N + n;
          if constexpr (EPI == 0) {
            Cb[idx] = f2b(c);
          } else if constexpr (EPI == 2) {
            float v = Xin[idx] + c * sc;
            Xout[idx] = v;
            if (Xb16) Xb16[idx] = f2b(v);
          } else if constexpr (EPI == 3) {
            float g = c + bias[n];
            float ge = 0.5f * g * (1.0f + erff(g * 0.70710678f));
            Cb[idx] = f2b(ge);
          } else {  // EPI 4
            float l = c + bias[n];
            Xout[idx] = Xin[idx] * sigmoidf_(l);
          }
        }
  }
}

// ---------------------------------------------------------------- windowed anti-causal decay attention
// R[b,t,:] = sum_{s>t} (q_t . k_s) * decay^(s-t-1) * v[s,:]
// Grid: (t-tiles of 64, NS=4 window segments, B). Each block writes its fp32 partial slab.
__global__ __launch_bounds__(256)
void attn_k(const u16* __restrict__ q, const u16* __restrict__ k,
            const u16* __restrict__ vT, float* __restrict__ Rp,
            const float* __restrict__ dlogit) {
  const int Tn = 4096, S = 256;
  __shared__ u16 kl[32 * 264];
  __shared__ u16 vtl[256 * 40];
  __shared__ u16 Pl[64 * 40];
  const int t0 = blockIdx.x * 64;
  const int jseg = blockIdx.y;
  const int b = blockIdx.z;
  const u16* qb = q + (size_t)b * Tn * S;
  const u16* kb = k + (size_t)b * Tn * S;
  const u16* vb_ = vT + (size_t)b * S * Tn;
  const float dec = sigmoidf_(dlogit[0]);
  const float ld = logf(dec);
  const float nmax = (ld < -1e-9f) ? (-30.0f / ld) : 1e30f;
  // number of 32-wide s-tiles with non-negligible weight, split across 4 segments
  const float wf = fminf(nmax + 65.0f, (float)(Tn - t0));
  const int tiles = ((int)wf + 31) >> 5;
  const int per = (tiles + 3) >> 2;
  const int i0 = jseg * per, i1 = min(tiles, i0 + per);
  const int tid = threadIdx.x, wid = tid >> 6, lane = tid & 63;
  const int lr = lane & 15, lk = (lane >> 4) * 8;
  s16x8 qa[8];
  {
    const u16* qr = qb + (size_t)(t0 + wid * 16 + lr) * S;
#pragma unroll
    for (int kk = 0; kk < 8; ++kk) qa[kk] = *(const s16x8*)&qr[kk * 32 + lk];
  }
  f32x4 racc[4][4] = {};
  for (int it = i0; it < i1; ++it) {
    const int s0 = t0 + it * 32;
#pragma unroll
    for (int p = 0; p < 4; ++p) {
      int c = tid + p * 256;
      {
        int row = c >> 5, c8 = (c & 31) * 8;
        *(uint4*)&kl[row * 264 + c8] = *(const uint4*)&kb[(size_t)(s0 + row) * S + c8];
      }
      {
        int d = c >> 2, c8 = (c & 3) * 8;
        *(uint4*)&vtl[d * 40 + c8] = *(const uint4*)&vb_[(size_t)d * Tn + s0 + c8];
      }
    }
    __syncthreads();
    f32x4 sc[2] = {};
#pragma unroll
    for (int kk = 0; kk < 8; ++kk) {
#pragma unroll
      for (int j = 0; j < 2; ++j) {
        s16x8 bf = *(const s16x8*)&kl[(j * 16 + lr) * 264 + kk * 32 + lk];
        sc[j] = mfma16(qa[kk], bf, sc[j]);
      }
    }
#pragma unroll
    for (int j = 0; j < 2; ++j)
#pragma unroll
      for (int r = 0; r < 4; ++r) {
        int tl = wid * 16 + (lane >> 4) * 4 + r;
        int sl = j * 16 + lr;
        int diff = (s0 + sl) - (t0 + tl);
        float pw = (diff > 0) ? expf(ld * (float)(diff - 1)) : 0.0f;
        Pl[tl * 40 + sl] = f2b(sc[j][r] * pw);
      }
    __syncthreads();
    {
      s16x8 pa[4], vv[4];
#pragma unroll
      for (int i = 0; i < 4; ++i) pa[i] = *(const s16x8*)&Pl[(i * 16 + lr) * 40 + lk];
#pragma unroll
      for (int j = 0; j < 4; ++j) vv[j] = *(const s16x8*)&vtl[(wid * 64 + j * 16 + lr) * 40 + lk];
#pragma unroll
      for (int i = 0; i < 4; ++i)
#pragma unroll
        for (int j = 0; j < 4; ++j) racc[i][j] = mfma16(pa[i], vv[j], racc[i][j]);
    }
    __syncthreads();
  }
#pragma unroll
  for (int i = 0; i < 4; ++i)
#pragma unroll
    for (int j = 0; j < 4; ++j)
#pragma unroll
      for (int r = 0; r < 4; ++r) {
        int tl = i * 16 + (lane >> 4) * 4 + r;
        int d = wid * 64 + j * 16 + lr;
        Rp[(((size_t)jseg * 2 + b) * Tn + t0 + tl) * S + d] = racc[i][j][r];
      }
}

// sum 4 fp32 partial slabs -> bf16 R
__global__ __launch_bounds__(256)
void attn_reduce(const float* __restrict__ Rp, u16* __restrict__ R) {
  const size_t stride = (size_t)2 * 4096 * 256;
  size_t i = ((size_t)blockIdx.x * 256 + threadIdx.x) * 4;
  float4 a = *(const float4*)(Rp + i);
  float4 b = *(const float4*)(Rp + i + stride);
  float4 c = *(const float4*)(Rp + i + 2 * stride);
  float4 d = *(const float4*)(Rp + i + 3 * stride);
  ushort4 o;
  o.x = f2b(a.x + b.x + c.x + d.x);
  o.y = f2b(a.y + b.y + c.y + d.y);
  o.z = f2b(a.z + b.z + c.z + d.z);
  o.w = f2b(a.w + b.w + c.w + d.w);
  *(ushort4*)(R + i) = o;
}

// ---------------------------------------------------------------- host
extern "C" void kernel_launch(void* const* d_in, const int* in_sizes, int n_in,
                              void* d_out, int out_size, void* d_ws, size_t ws_size,
                              hipStream_t stream) {
  const float* x0 = (const float*)d_in[0];
  const float* Wq = (const float*)d_in[1];
  const float* Wk = (const float*)d_in[2];
  const float* Wv = (const float*)d_in[3];
  const float* Wo = (const float*)d_in[4];
  const float* dlog = (const float*)d_in[5];
  const float* dscale = (const float*)d_in[6];
  const float* th_dec = (const float*)d_in[7];
  const float* th_sc = (const float*)d_in[8];
  const float* ga_dec = (const float*)d_in[9];
  const float* ga_sc = (const float*)d_in[10];
  const float* adw = (const float*)d_in[11];
  const float* auw = (const float*)d_in[12];
  const float* a_upb = (const float*)d_in[13];
  const float* bdw = (const float*)d_in[14];
  const float* buw = (const float*)d_in[15];
  const float* bbias = (const float*)d_in[16];
  const float* bscale = (const float*)d_in[17];

  char* w = (char*)d_ws;
  float* xA = (float*)w;                       // 33,554,432
  u16* y = (u16*)(w + 33554432);               // 16,777,216
  u16* xb = (u16*)(w + 50331648);              // 16,777,216
  u16* qb = (u16*)(w + 67108864);              // 4,194,304
  u16* kb = (u16*)(w + 71303168);              // 4,194,304
  u16* vT = (u16*)(w + 75497472);              // 4,194,304
  u16* Rb = (u16*)(w + 79691776);              // 4,194,304
  u16* gb = (u16*)(w + 83886080);              // 2,097,152
  u16* hb = (u16*)(w + 85983232);              // 33,554,432 (beta h; dead during attn)
  float* Rp = (float*)hb;                      // attn fp32 partials, 4 x 8.39 MB (aliases hb)
  float* Pp = (float*)(w + 119537664);         // 262,144
  u16* Wqb = (u16*)(w + 119799808);            // 524,288
  u16* Wkb = (u16*)(w + 120324096);
  u16* Wvb = (u16*)(w + 120848384);
  u16* Wob = (u16*)(w + 121372672);
  u16* adb = (u16*)(w + 121896960);            // 262,144
  u16* aub = (u16*)(w + 122159104);            // 262,144
  u16* bdb = (u16*)(w + 122421248);            // 4,194,304
  u16* bub = (u16*)(w + 126615552);            // 4,194,304
  float* xB = (float*)d_out;

  // weight casts
  cast_k<<<256, 256, 0, stream>>>(Wq, Wqb);
  cast_k<<<256, 256, 0, stream>>>(Wk, Wkb);
  cast_k<<<256, 256, 0, stream>>>(Wv, Wvb);
  cast_k<<<256, 256, 0, stream>>>(Wo, Wob);
  cast_k<<<128, 256, 0, stream>>>(adw, adb);
  cast_k<<<128, 256, 0, stream>>>(auw, aub);
  cast_k<<<2048, 256, 0, stream>>>(bdw, bdb);
  cast_k<<<2048, 256, 0, stream>>>(buw, bub);

  // ---- stage 1: x1 = x0 + delta(rmsnorm(x0))
  rmsnorm_k<<<8192, 256, 0, stream>>>(x0, y);
  delta_partial<<<dim3(4, 32, 2), 256, 0, stream>>>(y, dlog, Pp);
  delta_scan<<<dim3(4, 2), 256, 0, stream>>>(Pp);
  delta_apply<<<dim3(4, 32, 2), 256, 0, stream>>>(x0, y, dlog, dscale, Pp, xA);

  // ---- stage 2: x2 = x1 + memory(rmsnorm(x1), theta)
  rmsnorm_k<<<8192, 256, 0, stream>>>(xA, y);
  gemm_bt<0><<<dim3(2, 64), 256, 0, stream>>>(y, Wqb, 8192, 256, 1024, qb, nullptr, nullptr, nullptr, nullptr, nullptr);
  gemm_bt<0><<<dim3(2, 64), 256, 0, stream>>>(y, Wkb, 8192, 256, 1024, kb, nullptr, nullptr, nullptr, nullptr, nullptr);
  gemm_bt<1><<<dim3(2, 64), 256, 0, stream>>>(y, Wvb, 8192, 256, 1024, vT, nullptr, nullptr, nullptr, nullptr, nullptr);
  attn_k<<<dim3(64, 4, 2), 256, 0, stream>>>(qb, kb, vT, Rp, th_dec);
  attn_reduce<<<2048, 256, 0, stream>>>(Rp, Rb);
  gemm_bt<2><<<dim3(8, 64), 256, 0, stream>>>(Rb, Wob, 8192, 1024, 256, nullptr, xA, xB, xb, nullptr, th_sc);

  // ---- stage 3: x3 = alpha(x2)   (x2 fp32 in xB, bf16 in xb)
  gemm_bt<0><<<dim3(1, 64), 256, 0, stream>>>(xb, adb, 8192, 128, 1024, gb, nullptr, nullptr, nullptr, nullptr, nullptr);
  gemm_bt<4><<<dim3(8, 64), 256, 0, stream>>>(gb, aub, 8192, 1024, 128, nullptr, xB, xA, nullptr, a_upb, nullptr);

  // ---- stage 4: x4 = x3 + beta(rmsnorm(x3))
  rmsnorm_k<<<8192, 256, 0, stream>>>(xA, y);
  gemm_bt<3><<<dim3(16, 64), 256, 0, stream>>>(y, bdb, 8192, 2048, 1024, hb, nullptr, nullptr, nullptr, bbias, nullptr);
  gemm_bt<2><<<dim3(8, 64), 256, 0, stream>>>(hb, bub, 8192, 1024, 2048, nullptr, xA, xB, nullptr, nullptr, bscale);

  // ---- stage 5: out = x4 + memory(rmsnorm(x4), gamma)
  rmsnorm_k<<<8192, 256, 0, stream>>>(xB, y);
  gemm_bt<0><<<dim3(2, 64), 256, 0, stream>>>(y, Wqb, 8192, 256, 1024, qb, nullptr, nullptr, nullptr, nullptr, nullptr);
  gemm_bt<0><<<dim3(2, 64), 256, 0, stream>>>(y, Wkb, 8192, 256, 1024, kb, nullptr, nullptr, nullptr, nullptr, nullptr);
  gemm_bt<1><<<dim3(2, 64), 256, 0, stream>>>(y, Wvb, 8192, 256, 1024, vT, nullptr, nullptr, nullptr, nullptr, nullptr);
  attn_k<<<dim3(64, 4, 2), 256, 0, stream>>>(qb, kb, vT, Rp, ga_dec);
  attn_reduce<<<2048, 256, 0, stream>>>(Rp, Rb);
  gemm_bt<2><<<dim3(8, 64), 256, 0, stream>>>(Rb, Wob, 8192, 1024, 256, nullptr, xB, xB, nullptr, nullptr, ga_sc);
}

// Round 3
// 416.282 us; speedup vs baseline: 1.2809x; 1.2809x over previous
//
#include <hip/hip_runtime.h>

typedef __attribute__((ext_vector_type(8))) short s16x8;
typedef __attribute__((ext_vector_type(4))) float f32x4;
typedef unsigned short u16;

#define DEV __device__ __forceinline__

DEV u16 f2b(float f) {
  unsigned u = __builtin_bit_cast(unsigned, f);
  unsigned r = (u + 0x7FFFu + ((u >> 16) & 1u)) >> 16;
  return (u16)r;
}
DEV float b2f(u16 h) { return __builtin_bit_cast(float, (unsigned)h << 16); }
DEV f32x4 mfma16(s16x8 a, s16x8 b, f32x4 c) {
  return __builtin_amdgcn_mfma_f32_16x16x32_bf16(a, b, c, 0, 0, 0);
}
DEV float sigmoidf_(float x) { return 1.0f / (1.0f + expf(-x)); }

DEV void g2l16(const u16* g, u16* l) {
  __builtin_amdgcn_global_load_lds((const __attribute__((address_space(1))) void*)g,
                                   (__attribute__((address_space(3))) void*)l, 16, 0, 0);
}

#define BAR() __builtin_amdgcn_s_barrier()
#define WAITV6() asm volatile("s_waitcnt vmcnt(6)" ::: "memory")
#define WAITV0() asm volatile("s_waitcnt vmcnt(0)" ::: "memory")
#define WAITL0()                                         \
  do {                                                   \
    asm volatile("s_waitcnt lgkmcnt(0)" ::: "memory");   \
    __builtin_amdgcn_sched_barrier(0);                   \
  } while (0)

// ---------------------------------------------------------------- cast f32->bf16
__global__ __launch_bounds__(256) void cast_k(const float* __restrict__ s, u16* __restrict__ d) {
  size_t i = ((size_t)blockIdx.x * 256 + threadIdx.x) * 4;
  float4 v = *(const float4*)(s + i);
  ushort4 p; p.x = f2b(v.x); p.y = f2b(v.y); p.z = f2b(v.z); p.w = f2b(v.w);
  *(ushort4*)(d + i) = p;
}

// ---------------------------------------------------------------- rmsnorm (row = 1024)
__global__ __launch_bounds__(256) void rmsnorm_k(const float* __restrict__ x, u16* __restrict__ y) {
  const size_t row = blockIdx.x;
  const int tid = threadIdx.x;
  float4 v = ((const float4*)(x + row * 1024))[tid];
  float ss = v.x * v.x + v.y * v.y + v.z * v.z + v.w * v.w;
#pragma unroll
  for (int o = 32; o >= 1; o >>= 1) ss += __shfl_xor(ss, o);
  __shared__ float red[4];
  if ((tid & 63) == 0) red[tid >> 6] = ss;
  __syncthreads();
  float tot = red[0] + red[1] + red[2] + red[3];
  float rn = rsqrtf(tot * (1.0f / 1024.0f) + 1.1920929e-7f);
  ushort4 p;
  p.x = f2b(v.x * rn); p.y = f2b(v.y * rn); p.z = f2b(v.z * rn); p.w = f2b(v.w * rn);
  *(ushort4*)(y + row * 1024 + tid * 4) = p;
}

// ---------------------------------------------------------------- delta (3-phase chunked scan)
__global__ __launch_bounds__(256)
void delta_partial(const u16* __restrict__ y, const float* __restrict__ logits, float* __restrict__ Pp) {
  const int v = blockIdx.x * 256 + threadIdx.x;
  const int c = blockIdx.y, b = blockIdx.z;
  const float dec = sigmoidf_(logits[v]);
  const float ldc = logf(fmaxf(dec, 1e-6f));
  const u16* yp = y + ((size_t)b * 4096 + c * 128) * 1024 + v;
  float acc = 0.0f;
  for (int t = 0; t < 128; ++t) {
    float wgt = expf((float)(4095 - (c * 128 + t)) * ldc);
    acc += b2f(yp[(size_t)t * 1024]) * wgt;
  }
  Pp[((size_t)b * 32 + c) * 1024 + v] = acc;
}

__global__ __launch_bounds__(256) void delta_scan(float* __restrict__ Pp) {
  const int v = blockIdx.x * 256 + threadIdx.x;
  const int b = blockIdx.y;
  float run = 0.0f;
  for (int c = 0; c < 32; ++c) {
    size_t i = ((size_t)b * 32 + c) * 1024 + v;
    float t = Pp[i];
    Pp[i] = run;
    run += t;
  }
}

__global__ __launch_bounds__(256)
void delta_apply(const float* __restrict__ x0, const u16* __restrict__ y,
                 const float* __restrict__ logits, const float* __restrict__ scale_p,
                 const float* __restrict__ Pp, float* __restrict__ x1) {
  const int v = blockIdx.x * 256 + threadIdx.x;
  const int c = blockIdx.y, b = blockIdx.z;
  const float dec = sigmoidf_(logits[v]);
  const float ldc = logf(fmaxf(dec, 1e-6f));
  const float sc = scale_p[0];
  float carry = Pp[((size_t)b * 32 + c) * 1024 + v];
  size_t base = ((size_t)b * 4096 + c * 128) * 1024 + v;
  for (int t = 0; t < 128; ++t) {
    float wgt = expf((float)(4095 - (c * 128 + t)) * ldc);
    size_t idx = base + (size_t)t * 1024;
    x1[idx] = x0[idx] + carry / fmaxf(wgt, 1e-8f) * sc;
    carry += b2f(y[idx]) * wgt;
  }
}

// ---------------------------------------------------------------- pipelined GEMM (8-phase template)
// C[M,N] = A[M,K] * Bw[N,K]^T.  BM=128, BN=256, BK=64, 512 thr = 8 waves (2Mx4N).
// XOR-swizzled LDS (16B chunk col ^= row&7), pre-swizzled global source, counted vmcnt(6).
// EPI 2: Xout = Xin + C*scale (fp32), optional Xb16
// EPI 3: Cb = bf16(gelu(C + bias[n]))
// EPI 4: Xout = Xin * sigmoid(C + bias[n])
// EPI 5: qkv fused: bx==0 -> Cb (q, [m][256]); bx==1 -> P1 (k); bx==2 -> transpose to P2 (vT)
template <int EPI>
__global__ __launch_bounds__(512, 2)
void pgemm(const u16* __restrict__ A, const u16* __restrict__ Bw,
           int M, int N, int K,
           u16* __restrict__ Cb,
           const float* __restrict__ Xin, float* __restrict__ Xout,
           u16* __restrict__ Xb16,
           const float* __restrict__ bias, const float* __restrict__ scale_p,
           u16* __restrict__ P1, u16* __restrict__ P2) {
  __shared__ u16 sm[49152];  // 96 KB: 2 bufs x (A 128x64 + B 256x64)
  const int tid = threadIdx.x;
  const int wid = tid >> 6, lane = tid & 63;
  const int n0 = blockIdx.x * 256, m0 = blockIdx.y * 128;
  const int wm = (wid >> 2) * 64, wn = (wid & 3) * 64;
  const int lr = lane & 15, lkc = lane >> 4;
  const int sw = lr & 7;
  const int c0 = (lkc ^ sw) * 8, c1 = ((lkc + 4) ^ sw) * 8;  // swizzled k-chunk cols (u16)
  const int NT = K >> 6;
  const int srow = lane >> 3;
  const int scol = ((lane & 7) ^ srow) * 8;  // pre-swizzled source chunk
  const u16* Ag = A + (size_t)(m0 + wid * 8 + srow) * K + scol;
  const u16* Bg = Bw + (size_t)(n0 + wid * 8 + srow) * K + scol;
  u16* const AL0 = sm;          u16* const BL0 = sm + 8192;
  u16* const AL1 = sm + 24576;  u16* const BL1 = sm + 32768;

  f32x4 acc[4][4] = {};

  auto STA = [&](int tau) {  // 2 loads
    const u16* g = Ag + (size_t)tau * 64;
    u16* l = ((tau & 1) ? AL1 : AL0) + wid * 512;
    g2l16(g, l);
    g2l16(g + (size_t)64 * K, l + 4096);
  };
  auto STB = [&](int tau) {  // 4 loads (both halves)
    const u16* g = Bg + (size_t)tau * 64;
    u16* l = ((tau & 1) ? BL1 : BL0) + wid * 512;
    g2l16(g, l);
    g2l16(g + (size_t)64 * K, l + 4096);
    g2l16(g + (size_t)128 * K, l + 8192);
    g2l16(g + (size_t)192 * K, l + 12288);
  };
  auto RDA = [&](int tau, s16x8 (&d)[4][2]) {
    const u16* Ab = (tau & 1) ? AL1 : AL0;
#pragma unroll
    for (int i = 0; i < 4; ++i) {
      int base = (wm + i * 16 + lr) * 64;
      d[i][0] = *(const s16x8*)&Ab[base + c0];
      d[i][1] = *(const s16x8*)&Ab[base + c1];
    }
  };
  auto RDB = [&](int tau, int h, s16x8 (&d)[2][2]) {
    const u16* Bb = (tau & 1) ? BL1 : BL0;
#pragma unroll
    for (int j = 0; j < 2; ++j) {
      int base = (wn + h * 32 + j * 16 + lr) * 64;
      d[j][0] = *(const s16x8*)&Bb[base + c0];
      d[j][1] = *(const s16x8*)&Bb[base + c1];
    }
  };
  auto MM = [&](s16x8 (&Ar)[4][2], s16x8 (&Br)[2][2], int jo) {
    __builtin_amdgcn_s_setprio(1);
#pragma unroll
    for (int i = 0; i < 4; ++i)
#pragma unroll
      for (int j = 0; j < 2; ++j) {
        acc[i][jo + j] = mfma16(Ar[i][0], Br[j][0], acc[i][jo + j]);
        acc[i][jo + j] = mfma16(Ar[i][1], Br[j][1], acc[i][jo + j]);
      }
    __builtin_amdgcn_s_setprio(0);
  };

  s16x8 Ae[4][2], Ao[4][2], B0r[2][2], B1r[2][2];
  // prologue: stage tiles 0,1; force tile 0; initial reads
  STA(0); STB(0);
  if (NT > 1) { STA(1); STB(1); }
  WAITV6(); BAR();
  RDA(0, Ae); RDB(0, 0, B0r);

  for (int t = 0; t < NT; t += 2) {
    // ---- even tile t ---- phase A
    RDB(t, 1, B1r);
    if (t + 2 < NT) STA(t + 2);
    BAR(); WAITL0();
    MM(Ae, B0r, 0);
    BAR();
    // phase B
    if (t + 2 < NT) { STB(t + 2); WAITV6(); } else { WAITV0(); }
    BAR();
    if (t + 1 < NT) { RDA(t + 1, Ao); RDB(t + 1, 0, B0r); }
    WAITL0();
    MM(Ae, B1r, 2);
    BAR();
    if (t + 1 >= NT) break;
    // ---- odd tile t+1 ---- phase A
    RDB(t + 1, 1, B1r);
    if (t + 3 < NT) STA(t + 3);
    BAR(); WAITL0();
    MM(Ao, B0r, 0);
    BAR();
    // phase B
    if (t + 3 < NT) { STB(t + 3); WAITV6(); } else { WAITV0(); }
    BAR();
    if (t + 2 < NT) { RDA(t + 2, Ae); RDB(t + 2, 0, B0r); }
    WAITL0();
    MM(Ao, B1r, 2);
    BAR();
  }

  // ---------------- epilogue
  if constexpr (EPI == 5) {
    if (blockIdx.x < 2) {
      u16* dst = (blockIdx.x == 0) ? Cb : P1;
#pragma unroll
      for (int i = 0; i < 4; ++i)
#pragma unroll
        for (int j = 0; j < 4; ++j)
#pragma unroll
          for (int r = 0; r < 4; ++r) {
            int m = m0 + wm + i * 16 + lkc * 4 + r;
            int nl = wn + j * 16 + lr;
            dst[(size_t)m * 256 + nl] = f2b(acc[i][j][r]);
          }
    } else {
      u16* CT = sm;  // 256 x 136 bf16 = 68 KB < 96 KB
#pragma unroll
      for (int i = 0; i < 4; ++i)
#pragma unroll
        for (int j = 0; j < 4; ++j)
#pragma unroll
          for (int r = 0; r < 4; ++r) {
            int ml = wm + i * 16 + lkc * 4 + r;
            int nl = wn + j * 16 + lr;
            CT[nl * 136 + ml] = f2b(acc[i][j][r]);
          }
      BAR();
      int d = tid >> 1, off = (tid & 1) * 64;
      size_t base = ((size_t)(m0 >> 12) * 256 + d) * 4096 + (m0 & 4095) + off;
#pragma unroll
      for (int p = 0; p < 8; ++p)
        *(uint4*)&P2[base + p * 8] = *(const uint4*)&CT[d * 136 + off + p * 8];
    }
  } else {
    const float sc = (EPI == 2) ? scale_p[0] : 0.0f;
#pragma unroll
    for (int i = 0; i < 4; ++i)
#pragma unroll
      for (int j = 0; j < 4; ++j)
#pragma unroll
        for (int r = 0; r < 4; ++r) {
          int m = m0 + wm + i * 16 + lkc * 4 + r;
          int n = n0 + wn + j * 16 + lr;
          float c = acc[i][j][r];
          size_t idx = (size_t)m * N + n;
          if constexpr (EPI == 2) {
            float v = Xin[idx] + c * sc;
            Xout[idx] = v;
            if (Xb16) Xb16[idx] = f2b(v);
          } else if constexpr (EPI == 3) {
            float g = c + bias[n];
            float ge = 0.5f * g * (1.0f + erff(g * 0.70710678f));
            Cb[idx] = f2b(ge);
          } else if constexpr (EPI == 4) {
            float l = c + bias[n];
            Xout[idx] = Xin[idx] * sigmoidf_(l);
          }
        }
  }
}

// ---------------------------------------------------------------- small GEMM (alpha-down, N=128)
template <int EPI>
__global__ __launch_bounds__(256)
void gemm_bt(const u16* __restrict__ A, const u16* __restrict__ Bw,
             int M, int N, int K,
             u16* __restrict__ Cb) {
  __shared__ u16 sm[2 * 128 * 72];
  u16* As = sm;
  u16* Bs = sm + 128 * 64;
  const int tid = threadIdx.x;
  const int n0 = blockIdx.x * 128, m0 = blockIdx.y * 128;
  const int wid = tid >> 6, lane = tid & 63;
  const int wm = (wid >> 1) * 64, wn = (wid & 1) * 64;
  const int lr = lane & 15, lk = (lane >> 4) * 8;
  const int srow = lane >> 3, scol = (lane & 7) * 8;
  f32x4 acc[4][4] = {};
  for (int kt = 0; kt < K; kt += 64) {
#pragma unroll
    for (int p = 0; p < 4; ++p) {
      int c = wid * 4 + p;
      g2l16(&A[(size_t)(m0 + c * 8 + srow) * K + kt + scol], &As[c * 512]);
      g2l16(&Bw[(size_t)(n0 + c * 8 + srow) * K + kt + scol], &Bs[c * 512]);
    }
    __syncthreads();
#pragma unroll
    for (int kk = 0; kk < 64; kk += 32) {
      s16x8 af[4], bfr[4];
#pragma unroll
      for (int i = 0; i < 4; ++i) af[i] = *(const s16x8*)&As[(wm + i * 16 + lr) * 64 + kk + lk];
#pragma unroll
      for (int j = 0; j < 4; ++j) bfr[j] = *(const s16x8*)&Bs[(wn + j * 16 + lr) * 64 + kk + lk];
#pragma unroll
      for (int i = 0; i < 4; ++i)
#pragma unroll
        for (int j = 0; j < 4; ++j) acc[i][j] = mfma16(af[i], bfr[j], acc[i][j]);
    }
    __syncthreads();
  }
#pragma unroll
  for (int i = 0; i < 4; ++i)
#pragma unroll
    for (int j = 0; j < 4; ++j)
#pragma unroll
      for (int r = 0; r < 4; ++r) {
        int m = m0 + wm + i * 16 + (lane >> 4) * 4 + r;
        int n = n0 + wn + j * 16 + lr;
        Cb[(size_t)m * N + n] = f2b(acc[i][j][r]);
      }
}

// ---------------------------------------------------------------- windowed anti-causal decay attention
__global__ __launch_bounds__(256)
void attn_k(const u16* __restrict__ q, const u16* __restrict__ k,
            const u16* __restrict__ vT, float* __restrict__ Rp,
            const float* __restrict__ dlogit) {
  const int Tn = 4096, S = 256;
  __shared__ u16 kl[32 * 264];
  __shared__ u16 vtl[256 * 40];
  __shared__ u16 Pl[64 * 40];
  const int t0 = blockIdx.x * 64;
  const int jseg = blockIdx.y;
  const int b = blockIdx.z;
  const u16* qb = q + (size_t)b * Tn * S;
  const u16* kb = k + (size_t)b * Tn * S;
  const u16* vb_ = vT + (size_t)b * S * Tn;
  const float dec = sigmoidf_(dlogit[0]);
  const float ld = logf(dec);
  const float nmax = (ld < -1e-9f) ? (-30.0f / ld) : 1e30f;
  const float wf = fminf(nmax + 65.0f, (float)(Tn - t0));
  const int tiles = ((int)wf + 31) >> 5;
  const int per = (tiles + 3) >> 2;
  const int i0 = jseg * per, i1 = min(tiles, i0 + per);
  const int tid = threadIdx.x, wid = tid >> 6, lane = tid & 63;
  const int lr = lane & 15, lk = (lane >> 4) * 8;
  s16x8 qa[8];
  {
    const u16* qr = qb + (size_t)(t0 + wid * 16 + lr) * S;
#pragma unroll
    for (int kk = 0; kk < 8; ++kk) qa[kk] = *(const s16x8*)&qr[kk * 32 + lk];
  }
  f32x4 racc[4][4] = {};
  for (int it = i0; it < i1; ++it) {
    const int s0 = t0 + it * 32;
#pragma unroll
    for (int p = 0; p < 4; ++p) {
      int c = tid + p * 256;
      {
        int row = c >> 5, c8 = (c & 31) * 8;
        *(uint4*)&kl[row * 264 + c8] = *(const uint4*)&kb[(size_t)(s0 + row) * S + c8];
      }
      {
        int d = c >> 2, c8 = (c & 3) * 8;
        *(uint4*)&vtl[d * 40 + c8] = *(const uint4*)&vb_[(size_t)d * Tn + s0 + c8];
      }
    }
    __syncthreads();
    f32x4 sc[2] = {};
#pragma unroll
    for (int kk = 0; kk < 8; ++kk) {
#pragma unroll
      for (int j = 0; j < 2; ++j) {
        s16x8 bf = *(const s16x8*)&kl[(j * 16 + lr) * 264 + kk * 32 + lk];
        sc[j] = mfma16(qa[kk], bf, sc[j]);
      }
    }
#pragma unroll
    for (int j = 0; j < 2; ++j)
#pragma unroll
      for (int r = 0; r < 4; ++r) {
        int tl = wid * 16 + (lane >> 4) * 4 + r;
        int sl = j * 16 + lr;
        int diff = (s0 + sl) - (t0 + tl);
        float pw = (diff > 0) ? expf(ld * (float)(diff - 1)) : 0.0f;
        Pl[tl * 40 + sl] = f2b(sc[j][r] * pw);
      }
    __syncthreads();
    {
      s16x8 pa[4], vv[4];
#pragma unroll
      for (int i = 0; i < 4; ++i) pa[i] = *(const s16x8*)&Pl[(i * 16 + lr) * 40 + lk];
#pragma unroll
      for (int j = 0; j < 4; ++j) vv[j] = *(const s16x8*)&vtl[(wid * 64 + j * 16 + lr) * 40 + lk];
#pragma unroll
      for (int i = 0; i < 4; ++i)
#pragma unroll
        for (int j = 0; j < 4; ++j) racc[i][j] = mfma16(pa[i], vv[j], racc[i][j]);
    }
    __syncthreads();
  }
#pragma unroll
  for (int i = 0; i < 4; ++i)
#pragma unroll
    for (int j = 0; j < 4; ++j)
#pragma unroll
      for (int r = 0; r < 4; ++r) {
        int tl = i * 16 + (lane >> 4) * 4 + r;
        int d = wid * 64 + j * 16 + lr;
        Rp[(((size_t)jseg * 2 + b) * Tn + t0 + tl) * S + d] = racc[i][j][r];
      }
}

__global__ __launch_bounds__(256)
void attn_reduce(const float* __restrict__ Rp, u16* __restrict__ R) {
  const size_t stride = (size_t)2 * 4096 * 256;
  size_t i = ((size_t)blockIdx.x * 256 + threadIdx.x) * 4;
  float4 a = *(const float4*)(Rp + i);
  float4 b = *(const float4*)(Rp + i + stride);
  float4 c = *(const float4*)(Rp + i + 2 * stride);
  float4 d = *(const float4*)(Rp + i + 3 * stride);
  ushort4 o;
  o.x = f2b(a.x + b.x + c.x + d.x);
  o.y = f2b(a.y + b.y + c.y + d.y);
  o.z = f2b(a.z + b.z + c.z + d.z);
  o.w = f2b(a.w + b.w + c.w + d.w);
  *(ushort4*)(R + i) = o;
}

// ---------------------------------------------------------------- host
extern "C" void kernel_launch(void* const* d_in, const int* in_sizes, int n_in,
                              void* d_out, int out_size, void* d_ws, size_t ws_size,
                              hipStream_t stream) {
  const float* x0 = (const float*)d_in[0];
  const float* Wq = (const float*)d_in[1];
  const float* Wk = (const float*)d_in[2];
  const float* Wv = (const float*)d_in[3];
  const float* Wo = (const float*)d_in[4];
  const float* dlog = (const float*)d_in[5];
  const float* dscale = (const float*)d_in[6];
  const float* th_dec = (const float*)d_in[7];
  const float* th_sc = (const float*)d_in[8];
  const float* ga_dec = (const float*)d_in[9];
  const float* ga_sc = (const float*)d_in[10];
  const float* adw = (const float*)d_in[11];
  const float* auw = (const float*)d_in[12];
  const float* a_upb = (const float*)d_in[13];
  const float* bdw = (const float*)d_in[14];
  const float* buw = (const float*)d_in[15];
  const float* bbias = (const float*)d_in[16];
  const float* bscale = (const float*)d_in[17];

  char* w = (char*)d_ws;
  float* xA = (float*)w;                       // 33,554,432
  u16* y = (u16*)(w + 33554432);               // 16,777,216
  u16* xb = (u16*)(w + 50331648);              // 16,777,216
  u16* qb = (u16*)(w + 67108864);              // 4,194,304
  u16* kb = (u16*)(w + 71303168);              // 4,194,304
  u16* vT = (u16*)(w + 75497472);              // 4,194,304
  u16* Rb = (u16*)(w + 79691776);              // 4,194,304
  u16* gb = (u16*)(w + 83886080);              // 2,097,152
  u16* hb = (u16*)(w + 85983232);              // 33,554,432 (beta h; dead during attn)
  float* Rp = (float*)hb;                      // attn fp32 partials (aliases hb)
  float* Pp = (float*)(w + 119537664);         // 262,144
  u16* Wqkvb = (u16*)(w + 119799808);          // 1,572,864 ([768][1024])
  u16* Wob = (u16*)(w + 121372672);            // 524,288
  u16* adb = (u16*)(w + 121896960);            // 262,144
  u16* aub = (u16*)(w + 122159104);            // 262,144
  u16* bdb = (u16*)(w + 122421248);            // 4,194,304
  u16* bub = (u16*)(w + 126615552);            // 4,194,304
  float* xB = (float*)d_out;

  // weight casts (q,k,v fused into [768][1024])
  cast_k<<<256, 256, 0, stream>>>(Wq, Wqkvb);
  cast_k<<<256, 256, 0, stream>>>(Wk, Wqkvb + 262144);
  cast_k<<<256, 256, 0, stream>>>(Wv, Wqkvb + 524288);
  cast_k<<<256, 256, 0, stream>>>(Wo, Wob);
  cast_k<<<128, 256, 0, stream>>>(adw, adb);
  cast_k<<<128, 256, 0, stream>>>(auw, aub);
  cast_k<<<2048, 256, 0, stream>>>(bdw, bdb);
  cast_k<<<2048, 256, 0, stream>>>(buw, bub);

  // ---- stage 1: x1 = x0 + delta(rmsnorm(x0))
  rmsnorm_k<<<8192, 256, 0, stream>>>(x0, y);
  delta_partial<<<dim3(4, 32, 2), 256, 0, stream>>>(y, dlog, Pp);
  delta_scan<<<dim3(4, 2), 256, 0, stream>>>(Pp);
  delta_apply<<<dim3(4, 32, 2), 256, 0, stream>>>(x0, y, dlog, dscale, Pp, xA);

  // ---- stage 2: x2 = x1 + memory(rmsnorm(x1), theta)
  rmsnorm_k<<<8192, 256, 0, stream>>>(xA, y);
  pgemm<5><<<dim3(3, 64), 512, 0, stream>>>(y, Wqkvb, 8192, 768, 1024, qb, nullptr, nullptr, nullptr, nullptr, nullptr, kb, vT);
  attn_k<<<dim3(64, 4, 2), 256, 0, stream>>>(qb, kb, vT, Rp, th_dec);
  attn_reduce<<<2048, 256, 0, stream>>>(Rp, Rb);
  pgemm<2><<<dim3(4, 64), 512, 0, stream>>>(Rb, Wob, 8192, 1024, 256, nullptr, xA, xB, xb, nullptr, th_sc, nullptr, nullptr);

  // ---- stage 3: x3 = alpha(x2)
  gemm_bt<0><<<dim3(1, 64), 256, 0, stream>>>(xb, adb, 8192, 128, 1024, gb);
  pgemm<4><<<dim3(4, 64), 512, 0, stream>>>(gb, aub, 8192, 1024, 128, nullptr, xB, xA, nullptr, a_upb, nullptr, nullptr, nullptr);

  // ---- stage 4: x4 = x3 + beta(rmsnorm(x3))
  rmsnorm_k<<<8192, 256, 0, stream>>>(xA, y);
  pgemm<3><<<dim3(8, 64), 512, 0, stream>>>(y, bdb, 8192, 2048, 1024, hb, nullptr, nullptr, nullptr, bbias, nullptr, nullptr, nullptr);
  pgemm<2><<<dim3(4, 64), 512, 0, stream>>>(hb, bub, 8192, 1024, 2048, nullptr, xA, xB, nullptr, nullptr, bscale, nullptr, nullptr);

  // ---- stage 5: out = x4 + memory(rmsnorm(x4), gamma)
  rmsnorm_k<<<8192, 256, 0, stream>>>(xB, y);
  pgemm<5><<<dim3(3, 64), 512, 0, stream>>>(y, Wqkvb, 8192, 768, 1024, qb, nullptr, nullptr, nullptr, nullptr, nullptr, kb, vT);
  attn_k<<<dim3(64, 4, 2), 256, 0, stream>>>(qb, kb, vT, Rp, ga_dec);
  attn_reduce<<<2048, 256, 0, stream>>>(Rp, Rb);
  pgemm<2><<<dim3(4, 64), 512, 0, stream>>>(Rb, Wob, 8192, 1024, 256, nullptr, xB, xB, nullptr, nullptr, ga_sc, nullptr, nullptr);
}

// Round 5
// 381.799 us; speedup vs baseline: 1.3966x; 1.0903x over previous
//
#include <hip/hip_runtime.h>

typedef __attribute__((ext_vector_type(8))) short s16x8;
typedef __attribute__((ext_vector_type(4))) float f32x4;
typedef unsigned short u16;

#define DEV __device__ __forceinline__

DEV u16 f2b(float f) {
  unsigned u = __builtin_bit_cast(unsigned, f);
  unsigned r = (u + 0x7FFFu + ((u >> 16) & 1u)) >> 16;
  return (u16)r;
}
DEV float b2f(u16 h) { return __builtin_bit_cast(float, (unsigned)h << 16); }
DEV f32x4 mfma16(s16x8 a, s16x8 b, f32x4 c) {
  return __builtin_amdgcn_mfma_f32_16x16x32_bf16(a, b, c, 0, 0, 0);
}
DEV float sigmoidf_(float x) { return 1.0f / (1.0f + expf(-x)); }

DEV void g2l16(const u16* g, u16* l) {
  __builtin_amdgcn_global_load_lds((const __attribute__((address_space(1))) void*)g,
                                   (__attribute__((address_space(3))) void*)l, 16, 0, 0);
}

#define BAR() __builtin_amdgcn_s_barrier()
#define WAITV8() asm volatile("s_waitcnt vmcnt(8)" ::: "memory")
#define WAITV0() asm volatile("s_waitcnt vmcnt(0)" ::: "memory")
#define WAITL0()                                         \
  do {                                                   \
    asm volatile("s_waitcnt lgkmcnt(0)" ::: "memory");   \
    __builtin_amdgcn_sched_barrier(0);                   \
  } while (0)

// ---------------------------------------------------------------- cast f32->bf16
__global__ __launch_bounds__(256) void cast_k(const float* __restrict__ s, u16* __restrict__ d) {
  size_t i = ((size_t)blockIdx.x * 256 + threadIdx.x) * 4;
  float4 v = *(const float4*)(s + i);
  ushort4 p; p.x = f2b(v.x); p.y = f2b(v.y); p.z = f2b(v.z); p.w = f2b(v.w);
  *(ushort4*)(d + i) = p;
}

// ---------------------------------------------------------------- rmsnorm (row = 1024)
__global__ __launch_bounds__(256) void rmsnorm_k(const float* __restrict__ x, u16* __restrict__ y) {
  const size_t row = blockIdx.x;
  const int tid = threadIdx.x;
  float4 v = ((const float4*)(x + row * 1024))[tid];
  float ss = v.x * v.x + v.y * v.y + v.z * v.z + v.w * v.w;
#pragma unroll
  for (int o = 32; o >= 1; o >>= 1) ss += __shfl_xor(ss, o);
  __shared__ float red[4];
  if ((tid & 63) == 0) red[tid >> 6] = ss;
  __syncthreads();
  float tot = red[0] + red[1] + red[2] + red[3];
  float rn = rsqrtf(tot * (1.0f / 1024.0f) + 1.1920929e-7f);
  ushort4 p;
  p.x = f2b(v.x * rn); p.y = f2b(v.y * rn); p.z = f2b(v.z * rn); p.w = f2b(v.w * rn);
  *(ushort4*)(y + row * 1024 + tid * 4) = p;
}

// ---------------------------------------------------------------- delta (3-phase chunked scan)
__global__ __launch_bounds__(256)
void delta_partial(const u16* __restrict__ y, const float* __restrict__ logits, float* __restrict__ Pp) {
  const int v = blockIdx.x * 256 + threadIdx.x;
  const int c = blockIdx.y, b = blockIdx.z;
  const float dec = sigmoidf_(logits[v]);
  const float ldc = logf(fmaxf(dec, 1e-6f));
  const u16* yp = y + ((size_t)b * 4096 + c * 128) * 1024 + v;
  float acc = 0.0f;
  for (int t = 0; t < 128; ++t) {
    float wgt = expf((float)(4095 - (c * 128 + t)) * ldc);
    acc += b2f(yp[(size_t)t * 1024]) * wgt;
  }
  Pp[((size_t)b * 32 + c) * 1024 + v] = acc;
}

__global__ __launch_bounds__(256) void delta_scan(float* __restrict__ Pp) {
  const int v = blockIdx.x * 256 + threadIdx.x;
  const int b = blockIdx.y;
  float run = 0.0f;
  for (int c = 0; c < 32; ++c) {
    size_t i = ((size_t)b * 32 + c) * 1024 + v;
    float t = Pp[i];
    Pp[i] = run;
    run += t;
  }
}

__global__ __launch_bounds__(256)
void delta_apply(const float* __restrict__ x0, const u16* __restrict__ y,
                 const float* __restrict__ logits, const float* __restrict__ scale_p,
                 const float* __restrict__ Pp, float* __restrict__ x1) {
  const int v = blockIdx.x * 256 + threadIdx.x;
  const int c = blockIdx.y, b = blockIdx.z;
  const float dec = sigmoidf_(logits[v]);
  const float ldc = logf(fmaxf(dec, 1e-6f));
  const float sc = scale_p[0];
  float carry = Pp[((size_t)b * 32 + c) * 1024 + v];
  size_t base = ((size_t)b * 4096 + c * 128) * 1024 + v;
  for (int t = 0; t < 128; ++t) {
    float wgt = expf((float)(4095 - (c * 128 + t)) * ldc);
    size_t idx = base + (size_t)t * 1024;
    x1[idx] = x0[idx] + carry / fmaxf(wgt, 1e-8f) * sc;
    carry += b2f(y[idx]) * wgt;
  }
}

// ---------------------------------------------------------------- pipelined GEMM
// C[M,N] = A[M,K] * Bw[N,K]^T.  BM=128, BN=128, BK=64, 256 thr = 4 waves (2Mx2N).
// 64KB LDS double-buffer -> 2 blocks/CU. XOR-swizzled LDS + pre-swizzled global src.
// Counted vmcnt(8). Bijective XCD block swizzle (grids % 8 == 0).
// EPI 0: Cb = bf16(C)
// EPI 2: Xout = Xin + C*scale (fp32), optional Xb16
// EPI 3: Cb = bf16(gelu_tanh(C + bias[n]))
// EPI 4: Xout = Xin * sigmoid(C + bias[n])
// EPI 5: qkv fused over N=768: bx 0,1 -> q; 2,3 -> k; 4,5 -> transpose into vT
//        (NOTE: route by swizzled bx, NOT blockIdx.x)
template <int EPI>
__global__ __launch_bounds__(256, 2)
void pgemm(const u16* __restrict__ A, const u16* __restrict__ Bw,
           int M, int N, int K,
           u16* __restrict__ Cb,
           const float* __restrict__ Xin, float* __restrict__ Xout,
           u16* __restrict__ Xb16,
           const float* __restrict__ bias, const float* __restrict__ scale_p,
           u16* __restrict__ P1, u16* __restrict__ P2) {
  __shared__ u16 sm[32768];  // 64 KB: 2 bufs x (A 128x64 + B 128x64)
  const int tid = threadIdx.x;
  const int wid = tid >> 6, lane = tid & 63;
  // bijective XCD swizzle on flattened id (nwg divisible by 8)
  const int gx = gridDim.x;
  const int id = blockIdx.y * gx + blockIdx.x;
  const int q8 = (gx * gridDim.y) >> 3;
  const int nid = (id & 7) * q8 + (id >> 3);
  const int bx = nid % gx, by = nid / gx;
  const int n0 = bx * 128, m0 = by * 128;
  const int wm = (wid >> 1) * 64, wn = (wid & 1) * 64;
  const int lr = lane & 15, lkc = lane >> 4;
  const int sw = lr & 7;
  const int c0 = (lkc ^ sw) * 8, c1 = ((lkc + 4) ^ sw) * 8;  // swizzled k-chunk cols (u16)
  const int NT = K >> 6;
  const int srow = lane >> 3;
  const int scol = ((lane & 7) ^ srow) * 8;  // pre-swizzled source chunk
  const u16* Ag = A + (size_t)(m0 + wid * 8 + srow) * K + scol;
  const u16* Bg = Bw + (size_t)(n0 + wid * 8 + srow) * K + scol;
  u16* const AL0 = sm;          u16* const BL0 = sm + 8192;
  u16* const AL1 = sm + 16384;  u16* const BL1 = sm + 24576;

  f32x4 acc[4][4] = {};

  auto STA = [&](int tau) {  // 4 loads: A tile 128x64
    const u16* g = Ag + (size_t)tau * 64;
    u16* l = ((tau & 1) ? AL1 : AL0) + wid * 512;
#pragma unroll
    for (int c = 0; c < 4; ++c) g2l16(g + (size_t)c * 32 * K, l + c * 2048);
  };
  auto STB = [&](int tau) {  // 4 loads: B tile 128x64
    const u16* g = Bg + (size_t)tau * 64;
    u16* l = ((tau & 1) ? BL1 : BL0) + wid * 512;
#pragma unroll
    for (int c = 0; c < 4; ++c) g2l16(g + (size_t)c * 32 * K, l + c * 2048);
  };
  auto RDA = [&](int tau, s16x8 (&d)[4][2]) {
    const u16* Ab = (tau & 1) ? AL1 : AL0;
#pragma unroll
    for (int i = 0; i < 4; ++i) {
      int base = (wm + i * 16 + lr) * 64;
      d[i][0] = *(const s16x8*)&Ab[base + c0];
      d[i][1] = *(const s16x8*)&Ab[base + c1];
    }
  };
  auto RDB = [&](int tau, int h, s16x8 (&d)[2][2]) {
    const u16* Bb = (tau & 1) ? BL1 : BL0;
#pragma unroll
    for (int j = 0; j < 2; ++j) {
      int base = (wn + h * 32 + j * 16 + lr) * 64;
      d[j][0] = *(const s16x8*)&Bb[base + c0];
      d[j][1] = *(const s16x8*)&Bb[base + c1];
    }
  };
  auto MM = [&](s16x8 (&Ar)[4][2], s16x8 (&Br)[2][2], int jo) {
    __builtin_amdgcn_s_setprio(1);
#pragma unroll
    for (int i = 0; i < 4; ++i)
#pragma unroll
      for (int j = 0; j < 2; ++j) {
        acc[i][jo + j] = mfma16(Ar[i][0], Br[j][0], acc[i][jo + j]);
        acc[i][jo + j] = mfma16(Ar[i][1], Br[j][1], acc[i][jo + j]);
      }
    __builtin_amdgcn_s_setprio(0);
  };

  s16x8 Ae[4][2], Ao[4][2], B0r[2][2], B1r[2][2];
  // prologue: stage tiles 0,1; wait tile 0; initial reads
  STA(0); STB(0);
  if (NT > 1) { STA(1); STB(1); }
  WAITV8(); BAR();
  RDA(0, Ae); RDB(0, 0, B0r);

  for (int t = 0; t < NT; t += 2) {
    // ---- even tile t ---- phase A (computes n-half 0)
    RDB(t, 1, B1r);
    if (t + 2 < NT) STA(t + 2);
    BAR(); WAITL0();
    MM(Ae, B0r, 0);
    BAR();
    // phase B (computes n-half 1)
    if (t + 2 < NT) { STB(t + 2); WAITV8(); } else { WAITV0(); }
    BAR();
    if (t + 1 < NT) { RDA(t + 1, Ao); RDB(t + 1, 0, B0r); }
    WAITL0();
    MM(Ae, B1r, 2);
    BAR();
    if (t + 1 >= NT) break;
    // ---- odd tile t+1 ---- phase A
    RDB(t + 1, 1, B1r);
    if (t + 3 < NT) STA(t + 3);
    BAR(); WAITL0();
    MM(Ao, B0r, 0);
    BAR();
    // phase B
    if (t + 3 < NT) { STB(t + 3); WAITV8(); } else { WAITV0(); }
    BAR();
    if (t + 2 < NT) { RDA(t + 2, Ae); RDB(t + 2, 0, B0r); }
    WAITL0();
    MM(Ao, B1r, 2);
    BAR();
  }

  // ---------------- epilogue
  if constexpr (EPI == 5) {
    if (bx < 4) {
      u16* dst = (bx < 2) ? Cb : P1;
      const int nbase = (bx & 1) * 128;
#pragma unroll
      for (int i = 0; i < 4; ++i)
#pragma unroll
        for (int j = 0; j < 4; ++j)
#pragma unroll
          for (int r = 0; r < 4; ++r) {
            int m = m0 + wm + i * 16 + lkc * 4 + r;
            int nl = nbase + wn + j * 16 + lr;
            dst[(size_t)m * 256 + nl] = f2b(acc[i][j][r]);
          }
    } else {
      u16* CT = sm;  // 128 x 136 bf16 = 34 KB < 64 KB
#pragma unroll
      for (int i = 0; i < 4; ++i)
#pragma unroll
        for (int j = 0; j < 4; ++j)
#pragma unroll
          for (int r = 0; r < 4; ++r) {
            int ml = wm + i * 16 + lkc * 4 + r;
            int nl = wn + j * 16 + lr;
            CT[nl * 136 + ml] = f2b(acc[i][j][r]);
          }
      BAR();
      int d = tid >> 1, off = (tid & 1) * 64;
      size_t base = ((size_t)(m0 >> 12) * 256 + (bx - 4) * 128 + d) * 4096 + (m0 & 4095) + off;
#pragma unroll
      for (int p = 0; p < 8; ++p)
        *(uint4*)&P2[base + p * 8] = *(const uint4*)&CT[d * 136 + off + p * 8];
    }
  } else {
    const float sc = (EPI == 2) ? scale_p[0] : 0.0f;
#pragma unroll
    for (int i = 0; i < 4; ++i)
#pragma unroll
      for (int j = 0; j < 4; ++j)
#pragma unroll
        for (int r = 0; r < 4; ++r) {
          int m = m0 + wm + i * 16 + lkc * 4 + r;
          int n = n0 + wn + j * 16 + lr;
          float c = acc[i][j][r];
          size_t idx = (size_t)m * N + n;
          if constexpr (EPI == 0) {
            Cb[idx] = f2b(c);
          } else if constexpr (EPI == 2) {
            float v = Xin[idx] + c * sc;
            Xout[idx] = v;
            if (Xb16) Xb16[idx] = f2b(v);
          } else if constexpr (EPI == 3) {
            float g = c + bias[n];
            float ge = g * sigmoidf_(1.59576912f * fmaf(0.044715f * g, g * g, g));
            Cb[idx] = f2b(ge);
          } else if constexpr (EPI == 4) {
            float l = c + bias[n];
            Xout[idx] = Xin[idx] * sigmoidf_(l);
          }
        }
  }
}

// ---------------------------------------------------------------- windowed anti-causal decay attention
__global__ __launch_bounds__(256)
void attn_k(const u16* __restrict__ q, const u16* __restrict__ k,
            const u16* __restrict__ vT, float* __restrict__ Rp,
            const float* __restrict__ dlogit) {
  const int Tn = 4096, S = 256;
  __shared__ u16 kl[32 * 264];
  __shared__ u16 vtl[256 * 40];
  __shared__ u16 Pl[64 * 40];
  const int t0 = blockIdx.x * 64;
  const int jseg = blockIdx.y;
  const int b = blockIdx.z;
  const u16* qb = q + (size_t)b * Tn * S;
  const u16* kb = k + (size_t)b * Tn * S;
  const u16* vb_ = vT + (size_t)b * S * Tn;
  const float dec = sigmoidf_(dlogit[0]);
  const float ld = logf(dec);
  const float nmax = (ld < -1e-9f) ? (-30.0f / ld) : 1e30f;
  const float wf = fminf(nmax + 65.0f, (float)(Tn - t0));
  const int tiles = ((int)wf + 31) >> 5;
  const int per = (tiles + 3) >> 2;
  const int i0 = jseg * per, i1 = min(tiles, i0 + per);
  const int tid = threadIdx.x, wid = tid >> 6, lane = tid & 63;
  const int lr = lane & 15, lk = (lane >> 4) * 8;
  s16x8 qa[8];
  {
    const u16* qr = qb + (size_t)(t0 + wid * 16 + lr) * S;
#pragma unroll
    for (int kk = 0; kk < 8; ++kk) qa[kk] = *(const s16x8*)&qr[kk * 32 + lk];
  }
  f32x4 racc[4][4] = {};
  for (int it = i0; it < i1; ++it) {
    const int s0 = t0 + it * 32;
#pragma unroll
    for (int p = 0; p < 4; ++p) {
      int c = tid + p * 256;
      {
        int row = c >> 5, c8 = (c & 31) * 8;
        *(uint4*)&kl[row * 264 + c8] = *(const uint4*)&kb[(size_t)(s0 + row) * S + c8];
      }
      {
        int d = c >> 2, c8 = (c & 3) * 8;
        *(uint4*)&vtl[d * 40 + c8] = *(const uint4*)&vb_[(size_t)d * Tn + s0 + c8];
      }
    }
    __syncthreads();
    f32x4 sc[2] = {};
#pragma unroll
    for (int kk = 0; kk < 8; ++kk) {
#pragma unroll
      for (int j = 0; j < 2; ++j) {
        s16x8 bf = *(const s16x8*)&kl[(j * 16 + lr) * 264 + kk * 32 + lk];
        sc[j] = mfma16(qa[kk], bf, sc[j]);
      }
    }
#pragma unroll
    for (int j = 0; j < 2; ++j)
#pragma unroll
      for (int r = 0; r < 4; ++r) {
        int tl = wid * 16 + (lane >> 4) * 4 + r;
        int sl = j * 16 + lr;
        int diff = (s0 + sl) - (t0 + tl);
        float pw = (diff > 0) ? expf(ld * (float)(diff - 1)) : 0.0f;
        Pl[tl * 40 + sl] = f2b(sc[j][r] * pw);
      }
    __syncthreads();
    {
      s16x8 pa[4], vv[4];
#pragma unroll
      for (int i = 0; i < 4; ++i) pa[i] = *(const s16x8*)&Pl[(i * 16 + lr) * 40 + lk];
#pragma unroll
      for (int j = 0; j < 4; ++j) vv[j] = *(const s16x8*)&vtl[(wid * 64 + j * 16 + lr) * 40 + lk];
#pragma unroll
      for (int i = 0; i < 4; ++i)
#pragma unroll
        for (int j = 0; j < 4; ++j) racc[i][j] = mfma16(pa[i], vv[j], racc[i][j]);
    }
    __syncthreads();
  }
#pragma unroll
  for (int i = 0; i < 4; ++i)
#pragma unroll
    for (int j = 0; j < 4; ++j)
#pragma unroll
      for (int r = 0; r < 4; ++r) {
        int tl = i * 16 + (lane >> 4) * 4 + r;
        int d = wid * 64 + j * 16 + lr;
        Rp[(((size_t)jseg * 2 + b) * Tn + t0 + tl) * S + d] = racc[i][j][r];
      }
}

__global__ __launch_bounds__(256)
void attn_reduce(const float* __restrict__ Rp, u16* __restrict__ R) {
  const size_t stride = (size_t)2 * 4096 * 256;
  size_t i = ((size_t)blockIdx.x * 256 + threadIdx.x) * 4;
  float4 a = *(const float4*)(Rp + i);
  float4 b = *(const float4*)(Rp + i + stride);
  float4 c = *(const float4*)(Rp + i + 2 * stride);
  float4 d = *(const float4*)(Rp + i + 3 * stride);
  ushort4 o;
  o.x = f2b(a.x + b.x + c.x + d.x);
  o.y = f2b(a.y + b.y + c.y + d.y);
  o.z = f2b(a.z + b.z + c.z + d.z);
  o.w = f2b(a.w + b.w + c.w + d.w);
  *(ushort4*)(R + i) = o;
}

// ---------------------------------------------------------------- host
extern "C" void kernel_launch(void* const* d_in, const int* in_sizes, int n_in,
                              void* d_out, int out_size, void* d_ws, size_t ws_size,
                              hipStream_t stream) {
  const float* x0 = (const float*)d_in[0];
  const float* Wq = (const float*)d_in[1];
  const float* Wk = (const float*)d_in[2];
  const float* Wv = (const float*)d_in[3];
  const float* Wo = (const float*)d_in[4];
  const float* dlog = (const float*)d_in[5];
  const float* dscale = (const float*)d_in[6];
  const float* th_dec = (const float*)d_in[7];
  const float* th_sc = (const float*)d_in[8];
  const float* ga_dec = (const float*)d_in[9];
  const float* ga_sc = (const float*)d_in[10];
  const float* adw = (const float*)d_in[11];
  const float* auw = (const float*)d_in[12];
  const float* a_upb = (const float*)d_in[13];
  const float* bdw = (const float*)d_in[14];
  const float* buw = (const float*)d_in[15];
  const float* bbias = (const float*)d_in[16];
  const float* bscale = (const float*)d_in[17];

  char* w = (char*)d_ws;
  float* xA = (float*)w;                       // 33,554,432
  u16* y = (u16*)(w + 33554432);               // 16,777,216
  u16* xb = (u16*)(w + 50331648);              // 16,777,216
  u16* qb = (u16*)(w + 67108864);              // 4,194,304
  u16* kb = (u16*)(w + 71303168);              // 4,194,304
  u16* vT = (u16*)(w + 75497472);              // 4,194,304
  u16* Rb = (u16*)(w + 79691776);              // 4,194,304
  u16* gb = (u16*)(w + 83886080);              // 2,097,152
  u16* hb = (u16*)(w + 85983232);              // 33,554,432 (beta h; dead during attn)
  float* Rp = (float*)hb;                      // attn fp32 partials (aliases hb)
  float* Pp = (float*)(w + 119537664);         // 262,144
  u16* Wqkvb = (u16*)(w + 119799808);          // 1,572,864 ([768][1024])
  u16* Wob = (u16*)(w + 121372672);            // 524,288
  u16* adb = (u16*)(w + 121896960);            // 262,144
  u16* aub = (u16*)(w + 122159104);            // 262,144
  u16* bdb = (u16*)(w + 122421248);            // 4,194,304
  u16* bub = (u16*)(w + 126615552);            // 4,194,304
  float* xB = (float*)d_out;

  // weight casts (q,k,v fused into [768][1024])
  cast_k<<<256, 256, 0, stream>>>(Wq, Wqkvb);
  cast_k<<<256, 256, 0, stream>>>(Wk, Wqkvb + 262144);
  cast_k<<<256, 256, 0, stream>>>(Wv, Wqkvb + 524288);
  cast_k<<<256, 256, 0, stream>>>(Wo, Wob);
  cast_k<<<128, 256, 0, stream>>>(adw, adb);
  cast_k<<<128, 256, 0, stream>>>(auw, aub);
  cast_k<<<2048, 256, 0, stream>>>(bdw, bdb);
  cast_k<<<2048, 256, 0, stream>>>(buw, bub);

  // ---- stage 1: x1 = x0 + delta(rmsnorm(x0))
  rmsnorm_k<<<8192, 256, 0, stream>>>(x0, y);
  delta_partial<<<dim3(4, 32, 2), 256, 0, stream>>>(y, dlog, Pp);
  delta_scan<<<dim3(4, 2), 256, 0, stream>>>(Pp);
  delta_apply<<<dim3(4, 32, 2), 256, 0, stream>>>(x0, y, dlog, dscale, Pp, xA);

  // ---- stage 2: x2 = x1 + memory(rmsnorm(x1), theta)
  rmsnorm_k<<<8192, 256, 0, stream>>>(xA, y);
  pgemm<5><<<dim3(6, 64), 256, 0, stream>>>(y, Wqkvb, 8192, 768, 1024, qb, nullptr, nullptr, nullptr, nullptr, nullptr, kb, vT);
  attn_k<<<dim3(64, 4, 2), 256, 0, stream>>>(qb, kb, vT, Rp, th_dec);
  attn_reduce<<<2048, 256, 0, stream>>>(Rp, Rb);
  pgemm<2><<<dim3(8, 64), 256, 0, stream>>>(Rb, Wob, 8192, 1024, 256, nullptr, xA, xB, xb, nullptr, th_sc, nullptr, nullptr);

  // ---- stage 3: x3 = alpha(x2)
  pgemm<0><<<dim3(1, 64), 256, 0, stream>>>(xb, adb, 8192, 128, 1024, gb, nullptr, nullptr, nullptr, nullptr, nullptr, nullptr, nullptr);
  pgemm<4><<<dim3(8, 64), 256, 0, stream>>>(gb, aub, 8192, 1024, 128, nullptr, xB, xA, nullptr, a_upb, nullptr, nullptr, nullptr);

  // ---- stage 4: x4 = x3 + beta(rmsnorm(x3))
  rmsnorm_k<<<8192, 256, 0, stream>>>(xA, y);
  pgemm<3><<<dim3(16, 64), 256, 0, stream>>>(y, bdb, 8192, 2048, 1024, hb, nullptr, nullptr, nullptr, bbias, nullptr, nullptr, nullptr);
  pgemm<2><<<dim3(8, 64), 256, 0, stream>>>(hb, bub, 8192, 1024, 2048, nullptr, xA, xB, nullptr, nullptr, bscale, nullptr, nullptr);

  // ---- stage 5: out = x4 + memory(rmsnorm(x4), gamma)
  rmsnorm_k<<<8192, 256, 0, stream>>>(xB, y);
  pgemm<5><<<dim3(6, 64), 256, 0, stream>>>(y, Wqkvb, 8192, 768, 1024, qb, nullptr, nullptr, nullptr, nullptr, nullptr, kb, vT);
  attn_k<<<dim3(64, 4, 2), 256, 0, stream>>>(qb, kb, vT, Rp, ga_dec);
  attn_reduce<<<2048, 256, 0, stream>>>(Rp, Rb);
  pgemm<2><<<dim3(8, 64), 256, 0, stream>>>(Rb, Wob, 8192, 1024, 256, nullptr, xB, xB, nullptr, nullptr, ga_sc, nullptr, nullptr);
}